// Round 7
// baseline (405.091 us; speedup 1.0000x reference)
//
#include <hip/hip_runtime.h>
#include <hip/hip_bf16.h>
#include <math.h>

#define NN 50000
#define NE 800000
#define DIM 128
#define NH 4
#define HD 32
#define ATTN_SCALE 0.17677669529663687f   // 1/sqrt(32)
#define MTILE 64
#define GEMM_BLOCKS 782       // ceil(50000/64)
#define PTS 2048              // edges per scatter block

// K1: node hist | pack_qkv | Wx,b'
#define K1_HIST_N   782           // 1024 edges each (782*1024 >= NE)
#define K1_QKV_BASE 782           // +192 blocks
#define K1_WXB_BASE 974           // +65 blocks (2 rows each, 130 rows)
#define K1_GRID     1039
// K3: scatter | pack_out | QKV GEMM
#define K3_SCAT_N     391         // ceil(NE/PTS)
#define K3_PACKO_BASE 391         // +128
#define K3_GEMM_BASE  519         // +782
#define K3_GRID       1301

typedef unsigned int uint;
typedef unsigned short ushort;
typedef __attribute__((ext_vector_type(8))) short short8;   // 8 bf16 (4 VGPRs)
typedef __attribute__((ext_vector_type(4))) float f32x4;    // MFMA acc

__device__ inline ushort f2bf(float f) {
    __hip_bfloat16 h = __float2bfloat16(f);   // round-to-nearest
    return *(ushort*)&h;
}
__device__ inline float bflo(uint u) { return __uint_as_float(u << 16); }
__device__ inline float bfhi(uint u) { return __uint_as_float(u & 0xffff0000u); }

// ---------------------------------- K1: node hist | pack_qkv | Wx,b'
// nodecnt pre-zeroed by memset. All phases independent.
__global__ __launch_bounds__(256) void k1_kernel(
    const int* __restrict__ dst, int* __restrict__ nodecnt,
    const float* __restrict__ Wq, const float* __restrict__ Wk,
    const float* __restrict__ Wv, short* __restrict__ BpQKV,
    const float* __restrict__ Wo, const float* __restrict__ Wm,
    const float* __restrict__ bo, const float* __restrict__ bm,
    float* __restrict__ Wx, float* __restrict__ bprime)
{
    const int bid = blockIdx.x;
    const int tid = threadIdx.x;

    if (bid < K1_HIST_N) {
        // per-node histogram: direct device atomics (50000 counters, ~16 deep)
        const int e0 = bid * 1024;
        #pragma unroll
        for (int it = 0; it < 4; ++it) {
            const int e = e0 + it * 256 + tid;
            if (e < NE) atomicAdd(&nodecnt[dst[e]], 1);
        }
    } else if (bid < K1_WXB_BASE) {
        // pack Wq/Wk/Wv into MFMA fragment order
        const int idx = (bid - K1_QKV_BASE) * 256 + tid;     // < 49152
        const int j = idx & 7, lane = (idx >> 3) & 63;
        const int rest = idx >> 9;                           // kc*24 + nt
        const int nt = rest % 24, kc = rest / 24;
        const int k = kc * 32 + (lane >> 4) * 8 + j;
        const int n = nt * 16 + (lane & 15);
        const float* W = (n < 128) ? Wq : (n < 256 ? Wk : Wv);
        BpQKV[idx] = (short)f2bf(W[k * 128 + (n & 127)]);
    } else {
        // Wx = Wo @ Wm2 (rows 128..255 of Wm); row 128 = b'
        const int r = (bid - K1_WXB_BASE) * 2 + (tid >> 7);
        const int j = tid & 127;
        if (r < 128) {
            float acc = 0.f;
            for (int t = 0; t < 128; ++t)
                acc = fmaf(Wo[r * 128 + t], Wm[(128 + t) * 128 + j], acc);
            Wx[r * 128 + j] = acc;
        } else if (r == 128) {
            float acc = bm[j];
            for (int t = 0; t < 128; ++t)
                acc = fmaf(bo[t], Wm[(128 + t) * 128 + j], acc);
            bprime[j] = acc;
        }
    }
}

// --------------------------- scan: 50000-node exclusive scan, one block
// rowptr[i] = prefix; cursor[i] = prefix (consumed as scatter cursor).
__global__ __launch_bounds__(256) void scan_kernel(
    const int* __restrict__ nodecnt,
    int* __restrict__ rowptr, int* __restrict__ cursor)
{
    __shared__ int part[256];
    const int tid = threadIdx.x;
    const int i0 = tid * 196;                 // 256*196 = 50176 >= NN
    int s = 0;
    for (int k = 0; k < 196; ++k) {
        const int i = i0 + k;
        if (i < NN) s += nodecnt[i];
    }
    part[tid] = s;
    __syncthreads();
    for (int off = 1; off < 256; off <<= 1) {
        const int y = (tid >= off) ? part[tid - off] : 0;
        __syncthreads();
        part[tid] += y;
        __syncthreads();
    }
    int run = part[tid] - s;                  // exclusive prefix of this chunk
    for (int k = 0; k < 196; ++k) {
        const int i = i0 + k;
        if (i < NN) {
            rowptr[i] = run;
            cursor[i] = run;
            run += nodecnt[i];
        }
    }
    if (tid == 255) rowptr[NN] = run;         // == NE
}

// -------------------- K3: direct CSR scatter | pack_out | QKV GEMM
// Scatter writes ONE aligned 16B record per edge:
//   edata[pos] = { src, eb0|eb1<<16 (bf16), eb2|eb3<<16 (bf16), 0 }
__global__ __launch_bounds__(256) void k3_kernel(
    const int* __restrict__ src, const int* __restrict__ dst,
    const float* __restrict__ edge_attr, const float* __restrict__ We,
    int* __restrict__ cursor, uint4* __restrict__ edata,
    const float* __restrict__ Wm, const float* __restrict__ Wx,
    short* __restrict__ BpOut,
    const float* __restrict__ x, const short* __restrict__ BpQKV,
    ushort* __restrict__ Qb, ushort* __restrict__ KVb)
{
    const int bid = blockIdx.x;
    const int tid = threadIdx.x;

    if (bid < K3_SCAT_N) {
        float we[12];
        #pragma unroll
        for (int i = 0; i < 12; ++i) we[i] = We[i];
        const int e0 = bid * PTS;
        #pragma unroll
        for (int it = 0; it < 8; ++it) {
            const int e = e0 + it * 256 + tid;
            if (e < NE) {
                const int d = dst[e];
                const int s = src[e];
                const int pos = atomicAdd(&cursor[d], 1);
                const float a0 = edge_attr[e * 3 + 0];
                const float a1 = edge_attr[e * 3 + 1];
                const float a2 = edge_attr[e * 3 + 2];
                const float b0 = a0 * we[0] + a1 * we[4] + a2 * we[8];
                const float b1 = a0 * we[1] + a1 * we[5] + a2 * we[9];
                const float b2 = a0 * we[2] + a1 * we[6] + a2 * we[10];
                const float b3 = a0 * we[3] + a1 * we[7] + a2 * we[11];
                uint4 rec;
                rec.x = (uint)s;
                rec.y = (uint)f2bf(b0) | ((uint)f2bf(b1) << 16);
                rec.z = (uint)f2bf(b2) | ((uint)f2bf(b3) << 16);
                rec.w = 0u;
                edata[pos] = rec;
            }
        }
    } else if (bid < K3_GEMM_BASE) {
        // pack epilogue B operand [Wm1; Wx]
        const int idx = (bid - K3_PACKO_BASE) * 256 + tid;   // < 32768
        const int j = idx & 7, lane = (idx >> 3) & 63;
        const int rest = idx >> 9;                           // kc*8 + nt
        const int nt = rest & 7, kc = rest >> 3;
        const int k = kc * 32 + (lane >> 4) * 8 + j;
        const int n = nt * 16 + (lane & 15);
        const float v = (k < 128) ? Wm[k * 128 + n] : Wx[(k - 128) * 128 + n];
        BpOut[idx] = (short)f2bf(v);
    } else {
        // ---- QKV MFMA, A operand read fp32 + converted in-register
        const int qb = bid - K3_GEMM_BASE;
        const int wave = tid >> 6;
        const int lane = tid & 63;
        const int m = lane & 15, quad = lane >> 4;
        const int row0w = qb * MTILE + wave * 16;
        const int arow = row0w + m;
        const bool rowok = arow < NN;

        short8 a[4];
        if (rowok) {
            const float* xr = x + (size_t)arow * 128;
            #pragma unroll
            for (int kc = 0; kc < 4; ++kc) {
                const float4 f0 = *(const float4*)(xr + kc * 32 + quad * 8);
                const float4 f1 = *(const float4*)(xr + kc * 32 + quad * 8 + 4);
                short8 v;
                v[0] = (short)f2bf(f0.x); v[1] = (short)f2bf(f0.y);
                v[2] = (short)f2bf(f0.z); v[3] = (short)f2bf(f0.w);
                v[4] = (short)f2bf(f1.x); v[5] = (short)f2bf(f1.y);
                v[6] = (short)f2bf(f1.z); v[7] = (short)f2bf(f1.w);
                a[kc] = v;
            }
        } else {
            #pragma unroll
            for (int kc = 0; kc < 4; ++kc) a[kc] = (short8)(0);
        }

        const int NT = 24;
        for (int nt = 0; nt < NT; nt += 2) {
            f32x4 acc0 = {0.f, 0.f, 0.f, 0.f}, acc1 = {0.f, 0.f, 0.f, 0.f};
            #pragma unroll
            for (int kc = 0; kc < 4; ++kc) {
                const short8 b0 = *(const short8*)(BpQKV + ((size_t)(kc * NT + nt) * 64 + lane) * 8);
                const short8 b1 = *(const short8*)(BpQKV + ((size_t)(kc * NT + nt + 1) * 64 + lane) * 8);
                acc0 = __builtin_amdgcn_mfma_f32_16x16x32_bf16(a[kc], b0, acc0, 0, 0, 0);
                acc1 = __builtin_amdgcn_mfma_f32_16x16x32_bf16(a[kc], b1, acc1, 0, 0, 0);
            }
            #pragma unroll
            for (int t = 0; t < 2; ++t) {
                const f32x4 acc = t ? acc1 : acc0;
                const int c = (nt + t) * 16 + m;           // global col in [0,384)
                #pragma unroll
                for (int g = 0; g < 4; ++g) {
                    const int r = row0w + quad * 4 + g;
                    if (r < NN) {
                        if (c < 128) Qb[(size_t)r * 128 + c] = f2bf(acc[g]);
                        else        KVb[(size_t)r * 256 + (c - 128)] = f2bf(acc[g]);
                    }
                }
            }
        }
    }
}

// ---------------------------------------------------------------- OUT MFMA
__global__ __launch_bounds__(256) void out_mfma_kernel(
    const float* __restrict__ x, const ushort* __restrict__ aggb,
    const short* __restrict__ Bp, const float* __restrict__ bprime,
    float* __restrict__ out)
{
    const int wave = threadIdx.x >> 6;
    const int lane = threadIdx.x & 63;
    const int m = lane & 15, quad = lane >> 4;
    const int row0w = blockIdx.x * MTILE + wave * 16;
    const int arow = row0w + m;
    const bool rowok = arow < NN;

    short8 a[8];
    if (rowok) {
        const float* xr = x + (size_t)arow * 128;
        #pragma unroll
        for (int kc = 0; kc < 4; ++kc) {
            const float4 f0 = *(const float4*)(xr + kc * 32 + quad * 8);
            const float4 f1 = *(const float4*)(xr + kc * 32 + quad * 8 + 4);
            short8 v;
            v[0] = (short)f2bf(f0.x); v[1] = (short)f2bf(f0.y);
            v[2] = (short)f2bf(f0.z); v[3] = (short)f2bf(f0.w);
            v[4] = (short)f2bf(f1.x); v[5] = (short)f2bf(f1.y);
            v[6] = (short)f2bf(f1.z); v[7] = (short)f2bf(f1.w);
            a[kc] = v;
        }
        #pragma unroll
        for (int kc = 0; kc < 4; ++kc)
            a[4 + kc] = *(const short8*)(aggb + (size_t)arow * 128 + kc * 32 + quad * 8);
    } else {
        #pragma unroll
        for (int kc = 0; kc < 8; ++kc) a[kc] = (short8)(0);
    }

    const int NT = 8;
    for (int nt = 0; nt < NT; nt += 2) {
        f32x4 acc0 = {0.f, 0.f, 0.f, 0.f}, acc1 = {0.f, 0.f, 0.f, 0.f};
        #pragma unroll
        for (int kc = 0; kc < 8; ++kc) {
            const short8 b0 = *(const short8*)(Bp + ((size_t)(kc * NT + nt) * 64 + lane) * 8);
            const short8 b1 = *(const short8*)(Bp + ((size_t)(kc * NT + nt + 1) * 64 + lane) * 8);
            acc0 = __builtin_amdgcn_mfma_f32_16x16x32_bf16(a[kc], b0, acc0, 0, 0, 0);
            acc1 = __builtin_amdgcn_mfma_f32_16x16x32_bf16(a[kc], b1, acc1, 0, 0, 0);
        }
        #pragma unroll
        for (int t = 0; t < 2; ++t) {
            const f32x4 acc = t ? acc1 : acc0;
            const int c = (nt + t) * 16 + m;           // global col in [0,128)
            const float bb = bprime[c];
            #pragma unroll
            for (int g = 0; g < 4; ++g) {
                const int r = row0w + quad * 4 + g;
                if (r < NN) out[(size_t)r * 128 + c] = fmaxf(acc[g] + bb, 0.f);
            }
        }
    }
}

// ----------------------------------------- FUSED attn + softmax + aggregate
// One wave per node; 4 groups of 16 lanes, each group owns one edge.
// Side data = ONE 16B record/edge (broadcast load): {src, bf16x4 bias}.
// K|V interleaved (512B/node). Pinned at the random-gather service floor.
__global__ __launch_bounds__(256) void attn_agg_kernel(
    const ushort* __restrict__ Qb, const ushort* __restrict__ KVb,
    const int* __restrict__ rowptr, const uint4* __restrict__ edata,
    ushort* __restrict__ aggb)
{
    const int tid = threadIdx.x;
    const int d = blockIdx.x * 4 + (tid >> 6);
    const int lane = tid & 63;
    const int g = lane >> 4;          // edge slot within quad
    const int t = lane & 15;          // 8-dim chunk index
    const int h = t >> 2;             // head of this chunk
    const int begin = rowptr[d];
    const int end   = rowptr[d + 1];

    const uint4 uq = *(const uint4*)(Qb + (size_t)d * DIM + 8 * t);
    const float q0 = bflo(uq.x), q1 = bfhi(uq.x);
    const float q2 = bflo(uq.y), q3 = bfhi(uq.y);
    const float q4 = bflo(uq.z), q5 = bfhi(uq.z);
    const float q6 = bflo(uq.w), q7 = bfhi(uq.w);

    float ss = 0.f;
    float a0 = 0.f, a1 = 0.f, a2 = 0.f, a3 = 0.f;
    float a4 = 0.f, a5 = 0.f, a6 = 0.f, a7 = 0.f;

    if (begin < end) {
        int ec = begin + g;
        if (ec >= end) ec = end - 1;
        uint4 rec = edata[ec];

        for (int p = begin; p < end; p += 4) {
            const bool ok = (p + g) < end;
            const int pn = p + 4;
            uint4 recn = rec;
            if (pn < end) {
                int en = pn + g;
                if (en >= end) en = end - 1;
                recn = edata[en];
            }

            const int s = (int)rec.x;
            const uint wrd = (h & 2) ? rec.z : rec.y;
            const float eb = (h & 1) ? bfhi(wrd) : bflo(wrd);

            const ushort* kv = KVb + (size_t)s * 256 + 8 * t;
            const uint4 uk = *(const uint4*)(kv);
            const uint4 uv = *(const uint4*)(kv + 128);

            float da = q0 * bflo(uk.x);
            float db = q1 * bfhi(uk.x);
            da = fmaf(q2, bflo(uk.y), da);
            db = fmaf(q3, bfhi(uk.y), db);
            da = fmaf(q4, bflo(uk.z), da);
            db = fmaf(q5, bfhi(uk.z), db);
            da = fmaf(q6, bflo(uk.w), da);
            db = fmaf(q7, bfhi(uk.w), db);
            float part = da + db;
            part += __shfl_xor(part, 1);
            part += __shfl_xor(part, 2);

            float a = fmaf(part, ATTN_SCALE, eb);
            a = (a >= 0.f) ? a : 0.2f * a;
            const float w = ok ? __expf(a) : 0.f;

            ss += w;
            a0 = fmaf(w, bflo(uv.x), a0);
            a1 = fmaf(w, bfhi(uv.x), a1);
            a2 = fmaf(w, bflo(uv.y), a2);
            a3 = fmaf(w, bfhi(uv.y), a3);
            a4 = fmaf(w, bflo(uv.z), a4);
            a5 = fmaf(w, bfhi(uv.z), a5);
            a6 = fmaf(w, bflo(uv.w), a6);
            a7 = fmaf(w, bfhi(uv.w), a7);

            rec = recn;
        }
    }

    ss += __shfl_xor(ss, 16);
    ss += __shfl_xor(ss, 32);
    a0 += __shfl_xor(a0, 16); a0 += __shfl_xor(a0, 32);
    a1 += __shfl_xor(a1, 16); a1 += __shfl_xor(a1, 32);
    a2 += __shfl_xor(a2, 16); a2 += __shfl_xor(a2, 32);
    a3 += __shfl_xor(a3, 16); a3 += __shfl_xor(a3, 32);
    a4 += __shfl_xor(a4, 16); a4 += __shfl_xor(a4, 32);
    a5 += __shfl_xor(a5, 16); a5 += __shfl_xor(a5, 32);
    a6 += __shfl_xor(a6, 16); a6 += __shfl_xor(a6, 32);
    a7 += __shfl_xor(a7, 16); a7 += __shfl_xor(a7, 32);

    if (g == 0) {
        const float inv = 1.f / fmaxf(ss, 1e-12f);
        uint4 o;
        o.x = (uint)f2bf(a0 * inv) | ((uint)f2bf(a1 * inv) << 16);
        o.y = (uint)f2bf(a2 * inv) | ((uint)f2bf(a3 * inv) << 16);
        o.z = (uint)f2bf(a4 * inv) | ((uint)f2bf(a5 * inv) << 16);
        o.w = (uint)f2bf(a6 * inv) | ((uint)f2bf(a7 * inv) << 16);
        *(uint4*)(aggb + (size_t)d * DIM + 8 * t) = o;
    }
}

// ----------------------------------------------------------------- launch
extern "C" void kernel_launch(void* const* d_in, const int* in_sizes, int n_in,
                              void* d_out, int out_size, void* d_ws, size_t ws_size,
                              hipStream_t stream)
{
    const float* x         = (const float*)d_in[0];
    const int*   edge_idx  = (const int*)d_in[1];   // [2,E]: row0=src, row1=dst
    const float* edge_attr = (const float*)d_in[2];
    const float* Wq        = (const float*)d_in[3];
    const float* Wk        = (const float*)d_in[4];
    const float* Wv        = (const float*)d_in[5];
    const float* We        = (const float*)d_in[6];
    const float* Wo        = (const float*)d_in[7];
    const float* bo        = (const float*)d_in[8];
    const float* Wm        = (const float*)d_in[9];
    const float* bm        = (const float*)d_in[10];
    float* out = (float*)d_out;

    const int* src = edge_idx;
    const int* dst = edge_idx + NE;

    // workspace layout
    ushort* Qb   = (ushort*)d_ws;                       // NN*128 us
    ushort* KVb  = Qb + (size_t)NN * DIM;               // NN*256 us (K|V rows)
    ushort* aggb = KVb + (size_t)NN * 2 * DIM;          // NN*128 us
    uint4* edata = (uint4*)(aggb + (size_t)NN * DIM);   // NE uint4 (16B records)
    float* Wx    = (float*)(edata + NE);                // 16,384 f
    float* bprime= Wx + 16384;                          // 128 f
    short* BpQKV = (short*)(bprime + 128);              // 49,152 s
    short* BpOut = BpQKV + 49152;                       // 32,768 s
    int*   rowptr= (int*)(BpOut + 32768);               // 50,048 i (50001 used)
    int*   cursor = rowptr + 50048;                     // 50,048 i
    int*   nodecnt= cursor + 50048;                     // 50,048 i

    hipMemsetAsync(nodecnt, 0, 50048 * sizeof(int), stream);

    k1_kernel<<<K1_GRID, 256, 0, stream>>>(
        dst, nodecnt, Wq, Wk, Wv, BpQKV, Wo, Wm, bo, bm, Wx, bprime);

    scan_kernel<<<1, 256, 0, stream>>>(nodecnt, rowptr, cursor);

    k3_kernel<<<K3_GRID, 256, 0, stream>>>(
        src, dst, edge_attr, We, cursor, edata, Wm, Wx, BpOut,
        x, BpQKV, Qb, KVb);

    attn_agg_kernel<<<NN / 4, 256, 0, stream>>>(Qb, KVb, rowptr, edata, aggb);

    out_mfma_kernel<<<GEMM_BLOCKS, 256, 0, stream>>>(x, aggb, BpOut, bprime, out);
}

// Round 8
// 245.408 us; speedup vs baseline: 1.6507x; 1.6507x over previous
//
#include <hip/hip_runtime.h>
#include <hip/hip_bf16.h>
#include <math.h>

#define NN 50000
#define NE 800000
#define DIM 128
#define NH 4
#define HD 32
#define ATTN_SCALE 0.17677669529663687f   // 1/sqrt(32)
#define MTILE 64
#define GEMM_BLOCKS 782       // ceil(50000/64)
#define NBK 782               // fine buckets of 64 nodes: dst>>6
#define PTS 2048              // edges per partition block
#define HBLKS 104             // hist blocks: shallow atomic chains

// K1: hist + pack_qkv + Wx/b'
#define K1_QKV_BASE 104           // 192 blocks
#define K1_WXB_BASE 296           // 65 blocks (2 rows each, 130 rows)
#define K1_GRID     361
// K3: partition + pack_out + x->bf16
#define K3_PART_N     391         // ceil(NE/PTS)
#define K3_PACKO_BASE 391         // 128 blocks
#define K3_XCVT_BASE  519         // 6250 blocks
#define K3_GRID       6769
// K4: CSR (one block per fine bucket) + QKV GEMM
#define K4_CSR_N 782
#define K4_GRID  1564

typedef unsigned int uint;
typedef unsigned short ushort;
typedef __attribute__((ext_vector_type(8))) short short8;   // 8 bf16 (4 VGPRs)
typedef __attribute__((ext_vector_type(4))) float f32x4;    // MFMA acc

__device__ inline ushort f2bf(float f) {
    __hip_bfloat16 h = __float2bfloat16(f);   // round-to-nearest
    return *(ushort*)&h;
}
__device__ inline float bflo(uint u) { return __uint_as_float(u << 16); }
__device__ inline float bfhi(uint u) { return __uint_as_float(u & 0xffff0000u); }

// ---------------------------------------------- K1: hist | pack_qkv | Wx,b'
// bkt_cnt pre-zeroed by memset. All three phases independent.
__global__ __launch_bounds__(256) void k1_kernel(
    const int* __restrict__ dst, int* __restrict__ bkt_cnt,
    const float* __restrict__ Wq, const float* __restrict__ Wk,
    const float* __restrict__ Wv, short* __restrict__ BpQKV,
    const float* __restrict__ Wo, const float* __restrict__ Wm,
    const float* __restrict__ bo, const float* __restrict__ bm,
    float* __restrict__ Wx, float* __restrict__ bprime)
{
    const int bid = blockIdx.x;
    const int tid = threadIdx.x;

    if (bid < HBLKS) {
        // fine-bucket histogram (grid-stride over edges)
        __shared__ int c[NBK];
        for (int l = tid; l < NBK; l += 256) c[l] = 0;
        __syncthreads();
        for (int e = bid * 256 + tid; e < NE; e += HBLKS * 256)
            atomicAdd(&c[dst[e] >> 6], 1);
        __syncthreads();
        for (int l = tid; l < NBK; l += 256)
            if (c[l]) atomicAdd(&bkt_cnt[l], c[l]);
    } else if (bid < K1_WXB_BASE) {
        // pack Wq/Wk/Wv into MFMA fragment order
        const int idx = (bid - K1_QKV_BASE) * 256 + tid;     // < 49152
        const int j = idx & 7, lane = (idx >> 3) & 63;
        const int rest = idx >> 9;                           // kc*24 + nt
        const int nt = rest % 24, kc = rest / 24;
        const int k = kc * 32 + (lane >> 4) * 8 + j;
        const int n = nt * 16 + (lane & 15);
        const float* W = (n < 128) ? Wq : (n < 256 ? Wk : Wv);
        BpQKV[idx] = (short)f2bf(W[k * 128 + (n & 127)]);
    } else {
        // Wx = Wo @ Wm2 (rows 128..255 of Wm); row 128 = b'
        const int r = (bid - K1_WXB_BASE) * 2 + (tid >> 7);
        const int j = tid & 127;
        if (r < 128) {
            float acc = 0.f;
            for (int t = 0; t < 128; ++t)
                acc = fmaf(Wo[r * 128 + t], Wm[(128 + t) * 128 + j], acc);
            Wx[r * 128 + j] = acc;
        } else if (r == 128) {
            float acc = bm[j];
            for (int t = 0; t < 128; ++t)
                acc = fmaf(bo[t], Wm[(128 + t) * 128 + j], acc);
            bprime[j] = acc;
        }
    }
}

// -------------------------------------- K2: parallel 782-bucket excl. scan
__global__ __launch_bounds__(256) void bkt_scan_kernel(
    const int* __restrict__ bkt_cnt,
    int* __restrict__ bkt_base, int* __restrict__ bkt_cursor,
    int* __restrict__ rowptr)
{
    __shared__ int part[256];
    const int tid = threadIdx.x;
    const int b0 = tid * 4;
    int v0 = 0, v1 = 0, v2 = 0, v3 = 0;
    if (b0 + 0 < NBK) v0 = bkt_cnt[b0 + 0];
    if (b0 + 1 < NBK) v1 = bkt_cnt[b0 + 1];
    if (b0 + 2 < NBK) v2 = bkt_cnt[b0 + 2];
    if (b0 + 3 < NBK) v3 = bkt_cnt[b0 + 3];
    const int s = v0 + v1 + v2 + v3;
    part[tid] = s;
    __syncthreads();
    for (int off = 1; off < 256; off <<= 1) {
        const int y = (tid >= off) ? part[tid - off] : 0;
        __syncthreads();
        part[tid] += y;
        __syncthreads();
    }
    const int ex = part[tid] - s;
    const int r0 = ex, r1 = ex + v0, r2 = ex + v0 + v1, r3 = ex + v0 + v1 + v2;
    if (b0 + 0 < NBK) { bkt_base[b0 + 0] = r0; bkt_cursor[b0 + 0] = r0; }
    if (b0 + 1 < NBK) { bkt_base[b0 + 1] = r1; bkt_cursor[b0 + 1] = r1; }
    if (b0 + 2 < NBK) { bkt_base[b0 + 2] = r2; bkt_cursor[b0 + 2] = r2; }
    if (b0 + 3 < NBK) { bkt_base[b0 + 3] = r3; bkt_cursor[b0 + 3] = r3; }
    if (tid == 255) bkt_base[NBK] = part[255];   // == NE
    if (tid == 0)   rowptr[NN] = NE;
}

// ------------------------------- K3: partition | pack_out | x->bf16 stream
__global__ __launch_bounds__(256) void k3_kernel(
    const int* __restrict__ src, const int* __restrict__ dst,
    const float* __restrict__ edge_attr, const float* __restrict__ We,
    int* __restrict__ bkt_cursor,
    uint* __restrict__ ppack, uint2* __restrict__ pebp,
    const float* __restrict__ Wm, const float* __restrict__ Wx,
    short* __restrict__ BpOut,
    const float* __restrict__ x, ushort* __restrict__ xb)
{
    const int bid = blockIdx.x;
    const int tid = threadIdx.x;

    if (bid < K3_PART_N) {
        __shared__ int cnt[NBK], rbase[NBK], cnt2[NBK];
        for (int l = tid; l < NBK; l += 256) cnt[l] = 0;
        __syncthreads();
        const int e0 = bid * PTS;
        #pragma unroll
        for (int it = 0; it < 8; ++it) {
            const int e = e0 + it * 256 + tid;
            if (e < NE) atomicAdd(&cnt[dst[e] >> 6], 1);
        }
        __syncthreads();
        for (int l = tid; l < NBK; l += 256) {
            const int c = cnt[l];
            rbase[l] = c ? atomicAdd(&bkt_cursor[l], c) : 0;
            cnt2[l] = 0;
        }
        __syncthreads();
        #pragma unroll
        for (int it = 0; it < 8; ++it) {
            const int e = e0 + it * 256 + tid;
            if (e < NE) {
                const int d = dst[e];
                const int b = d >> 6;
                const int r = atomicAdd(&cnt2[b], 1);
                const int pos = rbase[b] + r;
                ppack[pos] = (uint)src[e] | ((uint)(d & 63) << 16);
                const float a0 = edge_attr[e * 3 + 0];
                const float a1 = edge_attr[e * 3 + 1];
                const float a2 = edge_attr[e * 3 + 2];
                const float b0 = a0 * We[0] + a1 * We[4] + a2 * We[8];
                const float b1 = a0 * We[1] + a1 * We[5] + a2 * We[9];
                const float b2 = a0 * We[2] + a1 * We[6] + a2 * We[10];
                const float b3 = a0 * We[3] + a1 * We[7] + a2 * We[11];
                uint2 ep;
                ep.x = (uint)f2bf(b0) | ((uint)f2bf(b1) << 16);
                ep.y = (uint)f2bf(b2) | ((uint)f2bf(b3) << 16);
                pebp[pos] = ep;
            }
        }
    } else if (bid < K3_XCVT_BASE) {
        // pack epilogue B operand [Wm1; Wx]
        const int idx = (bid - K3_PACKO_BASE) * 256 + tid;   // < 32768
        const int j = idx & 7, lane = (idx >> 3) & 63;
        const int rest = idx >> 9;                           // kc*8 + nt
        const int nt = rest & 7, kc = rest >> 3;
        const int k = kc * 32 + (lane >> 4) * 8 + j;
        const int n = nt * 16 + (lane & 15);
        const float v = (k < 128) ? Wm[k * 128 + n] : Wx[(k - 128) * 128 + n];
        BpOut[idx] = (short)f2bf(v);
    } else {
        // x -> bf16 (one float4 per thread)
        const int i = (bid - K3_XCVT_BASE) * 256 + tid;      // < 1,600,000
        const float4 v = ((const float4*)x)[i];
        ushort4 o;
        o.x = f2bf(v.x); o.y = f2bf(v.y); o.z = f2bf(v.z); o.w = f2bf(v.w);
        ((ushort4*)xb)[i] = o;
    }
}

// ------------------------- K4: CSR scatter (1 block per fine bucket) | QKV
// Scatter now emits ONE aligned 16B record per edge:
//   edata[pos] = { src, eb0|eb1 (bf16), eb2|eb3 (bf16), 0 }
// (was 2B srcp + 8B ebq = two random sub-sector stores per edge).
__global__ __launch_bounds__(256) void k4_kernel(
    const int* __restrict__ bkt_base,
    const uint* __restrict__ ppack, const uint2* __restrict__ pebp,
    int* __restrict__ rowptr, uint4* __restrict__ edata,
    const ushort* __restrict__ xb, const short* __restrict__ BpQKV,
    ushort* __restrict__ Qb, ushort* __restrict__ KVb)
{
    const int bid = blockIdx.x;
    const int tid = threadIdx.x;

    if (bid < K4_CSR_N) {
        __shared__ int cnt[64];
        __shared__ int pre[64];
        const int base = bkt_base[bid];
        const int n = bkt_base[bid + 1] - base;
        const int node0 = bid << 6;

        if (tid < 64) cnt[tid] = 0;
        __syncthreads();
        for (int i = base + tid; i < base + n; i += 256)
            atomicAdd(&cnt[ppack[i] >> 16], 1);
        __syncthreads();

        if (tid < 64) {
            const int c = cnt[tid];
            int xsc = c;                      // inclusive scan over wave 0
            #pragma unroll
            for (int off = 1; off < 64; off <<= 1) {
                const int y = __shfl_up(xsc, off);
                if (tid >= off) xsc += y;
            }
            const int ex = base + xsc - c;    // exclusive
            pre[tid] = ex;
            const int g = node0 + tid;
            if (g < NN) rowptr[g] = ex;
        }
        __syncthreads();

        for (int i = base + tid; i < base + n; i += 256) {
            const uint v = ppack[i];
            const int pos = atomicAdd(&pre[v >> 16], 1);
            const uint2 ep = pebp[i];
            uint4 rec;
            rec.x = v & 0xFFFFu;
            rec.y = ep.x;
            rec.z = ep.y;
            rec.w = 0u;
            edata[pos] = rec;
        }
    } else {
        // ---- QKV MFMA: Q -> Qb; K,V interleaved per node in KVb (512B rows)
        const int qb = bid - K4_CSR_N;
        const int wave = tid >> 6;
        const int lane = tid & 63;
        const int m = lane & 15, quad = lane >> 4;
        const int row0w = qb * MTILE + wave * 16;
        const int arow = row0w + m;
        const bool rowok = arow < NN;

        short8 a[4];
        #pragma unroll
        for (int kc = 0; kc < 4; ++kc)
            a[kc] = rowok ? *(const short8*)(xb + (size_t)arow * 128 + kc * 32 + quad * 8)
                          : (short8)(0);

        const int NT = 24;
        for (int nt = 0; nt < NT; nt += 2) {
            f32x4 acc0 = {0.f, 0.f, 0.f, 0.f}, acc1 = {0.f, 0.f, 0.f, 0.f};
            #pragma unroll
            for (int kc = 0; kc < 4; ++kc) {
                const short8 b0 = *(const short8*)(BpQKV + ((size_t)(kc * NT + nt) * 64 + lane) * 8);
                const short8 b1 = *(const short8*)(BpQKV + ((size_t)(kc * NT + nt + 1) * 64 + lane) * 8);
                acc0 = __builtin_amdgcn_mfma_f32_16x16x32_bf16(a[kc], b0, acc0, 0, 0, 0);
                acc1 = __builtin_amdgcn_mfma_f32_16x16x32_bf16(a[kc], b1, acc1, 0, 0, 0);
            }
            #pragma unroll
            for (int t = 0; t < 2; ++t) {
                const f32x4 acc = t ? acc1 : acc0;
                const int c = (nt + t) * 16 + m;           // global col in [0,384)
                #pragma unroll
                for (int g = 0; g < 4; ++g) {
                    const int r = row0w + quad * 4 + g;
                    if (r < NN) {
                        if (c < 128) Qb[(size_t)r * 128 + c] = f2bf(acc[g]);
                        else        KVb[(size_t)r * 256 + (c - 128)] = f2bf(acc[g]);
                    }
                }
            }
        }
    }
}

// ---------------------------------------------------------------- OUT MFMA
__global__ __launch_bounds__(256) void out_mfma_kernel(
    const ushort* __restrict__ xb, const ushort* __restrict__ aggb,
    const short* __restrict__ Bp, const float* __restrict__ bprime,
    float* __restrict__ out)
{
    const int wave = threadIdx.x >> 6;
    const int lane = threadIdx.x & 63;
    const int m = lane & 15, quad = lane >> 4;
    const int row0w = blockIdx.x * MTILE + wave * 16;
    const int arow = row0w + m;
    const bool rowok = arow < NN;

    short8 a[8];
    #pragma unroll
    for (int kc = 0; kc < 4; ++kc)
        a[kc] = rowok ? *(const short8*)(xb + (size_t)arow * 128 + kc * 32 + quad * 8)
                      : (short8)(0);
    #pragma unroll
    for (int kc = 0; kc < 4; ++kc)
        a[4 + kc] = rowok ? *(const short8*)(aggb + (size_t)arow * 128 + kc * 32 + quad * 8)
                          : (short8)(0);

    const int NT = 8;
    for (int nt = 0; nt < NT; nt += 2) {
        f32x4 acc0 = {0.f, 0.f, 0.f, 0.f}, acc1 = {0.f, 0.f, 0.f, 0.f};
        #pragma unroll
        for (int kc = 0; kc < 8; ++kc) {
            const short8 b0 = *(const short8*)(Bp + ((size_t)(kc * NT + nt) * 64 + lane) * 8);
            const short8 b1 = *(const short8*)(Bp + ((size_t)(kc * NT + nt + 1) * 64 + lane) * 8);
            acc0 = __builtin_amdgcn_mfma_f32_16x16x32_bf16(a[kc], b0, acc0, 0, 0, 0);
            acc1 = __builtin_amdgcn_mfma_f32_16x16x32_bf16(a[kc], b1, acc1, 0, 0, 0);
        }
        #pragma unroll
        for (int t = 0; t < 2; ++t) {
            const f32x4 acc = t ? acc1 : acc0;
            const int c = (nt + t) * 16 + m;           // global col in [0,128)
            const float bb = bprime[c];
            #pragma unroll
            for (int g = 0; g < 4; ++g) {
                const int r = row0w + quad * 4 + g;
                if (r < NN) out[(size_t)r * 128 + c] = fmaxf(acc[g] + bb, 0.f);
            }
        }
    }
}

// ----------------------------------------- FUSED attn + softmax + aggregate
// One wave per node; 4 groups of 16 lanes, each group owns one edge.
// Side data = ONE 16B record/edge (broadcast load): {src, bf16x4 bias}.
// K|V interleaved (512B/node). Pinned at the random-gather service floor.
__global__ __launch_bounds__(256) void attn_agg_kernel(
    const ushort* __restrict__ Qb, const ushort* __restrict__ KVb,
    const int* __restrict__ rowptr, const uint4* __restrict__ edata,
    ushort* __restrict__ aggb)
{
    const int tid = threadIdx.x;
    const int d = blockIdx.x * 4 + (tid >> 6);
    const int lane = tid & 63;
    const int g = lane >> 4;          // edge slot within quad
    const int t = lane & 15;          // 8-dim chunk index
    const int h = t >> 2;             // head of this chunk
    const int begin = rowptr[d];
    const int end   = rowptr[d + 1];

    const uint4 uq = *(const uint4*)(Qb + (size_t)d * DIM + 8 * t);
    const float q0 = bflo(uq.x), q1 = bfhi(uq.x);
    const float q2 = bflo(uq.y), q3 = bfhi(uq.y);
    const float q4 = bflo(uq.z), q5 = bfhi(uq.z);
    const float q6 = bflo(uq.w), q7 = bfhi(uq.w);

    float ss = 0.f;
    float a0 = 0.f, a1 = 0.f, a2 = 0.f, a3 = 0.f;
    float a4 = 0.f, a5 = 0.f, a6 = 0.f, a7 = 0.f;

    if (begin < end) {
        int ec = begin + g;
        if (ec >= end) ec = end - 1;
        uint4 rec = edata[ec];

        for (int p = begin; p < end; p += 4) {
            const bool ok = (p + g) < end;
            const int pn = p + 4;
            uint4 recn = rec;
            if (pn < end) {
                int en = pn + g;
                if (en >= end) en = end - 1;
                recn = edata[en];
            }

            const int s = (int)rec.x;
            const uint wrd = (h & 2) ? rec.z : rec.y;
            const float eb = (h & 1) ? bfhi(wrd) : bflo(wrd);

            const ushort* kv = KVb + (size_t)s * 256 + 8 * t;
            const uint4 uk = *(const uint4*)(kv);
            const uint4 uv = *(const uint4*)(kv + 128);

            float da = q0 * bflo(uk.x);
            float db = q1 * bfhi(uk.x);
            da = fmaf(q2, bflo(uk.y), da);
            db = fmaf(q3, bfhi(uk.y), db);
            da = fmaf(q4, bflo(uk.z), da);
            db = fmaf(q5, bfhi(uk.z), db);
            da = fmaf(q6, bflo(uk.w), da);
            db = fmaf(q7, bfhi(uk.w), db);
            float part = da + db;
            part += __shfl_xor(part, 1);
            part += __shfl_xor(part, 2);

            float a = fmaf(part, ATTN_SCALE, eb);
            a = (a >= 0.f) ? a : 0.2f * a;
            const float w = ok ? __expf(a) : 0.f;

            ss += w;
            a0 = fmaf(w, bflo(uv.x), a0);
            a1 = fmaf(w, bfhi(uv.x), a1);
            a2 = fmaf(w, bflo(uv.y), a2);
            a3 = fmaf(w, bfhi(uv.y), a3);
            a4 = fmaf(w, bflo(uv.z), a4);
            a5 = fmaf(w, bfhi(uv.z), a5);
            a6 = fmaf(w, bflo(uv.w), a6);
            a7 = fmaf(w, bfhi(uv.w), a7);

            rec = recn;
        }
    }

    ss += __shfl_xor(ss, 16);
    ss += __shfl_xor(ss, 32);
    a0 += __shfl_xor(a0, 16); a0 += __shfl_xor(a0, 32);
    a1 += __shfl_xor(a1, 16); a1 += __shfl_xor(a1, 32);
    a2 += __shfl_xor(a2, 16); a2 += __shfl_xor(a2, 32);
    a3 += __shfl_xor(a3, 16); a3 += __shfl_xor(a3, 32);
    a4 += __shfl_xor(a4, 16); a4 += __shfl_xor(a4, 32);
    a5 += __shfl_xor(a5, 16); a5 += __shfl_xor(a5, 32);
    a6 += __shfl_xor(a6, 16); a6 += __shfl_xor(a6, 32);
    a7 += __shfl_xor(a7, 16); a7 += __shfl_xor(a7, 32);

    if (g == 0) {
        const float inv = 1.f / fmaxf(ss, 1e-12f);
        uint4 o;
        o.x = (uint)f2bf(a0 * inv) | ((uint)f2bf(a1 * inv) << 16);
        o.y = (uint)f2bf(a2 * inv) | ((uint)f2bf(a3 * inv) << 16);
        o.z = (uint)f2bf(a4 * inv) | ((uint)f2bf(a5 * inv) << 16);
        o.w = (uint)f2bf(a6 * inv) | ((uint)f2bf(a7 * inv) << 16);
        *(uint4*)(aggb + (size_t)d * DIM + 8 * t) = o;
    }
}

// ----------------------------------------------------------------- launch
extern "C" void kernel_launch(void* const* d_in, const int* in_sizes, int n_in,
                              void* d_out, int out_size, void* d_ws, size_t ws_size,
                              hipStream_t stream)
{
    const float* x         = (const float*)d_in[0];
    const int*   edge_idx  = (const int*)d_in[1];   // [2,E]: row0=src, row1=dst
    const float* edge_attr = (const float*)d_in[2];
    const float* Wq        = (const float*)d_in[3];
    const float* Wk        = (const float*)d_in[4];
    const float* Wv        = (const float*)d_in[5];
    const float* We        = (const float*)d_in[6];
    const float* Wo        = (const float*)d_in[7];
    const float* bo        = (const float*)d_in[8];
    const float* Wm        = (const float*)d_in[9];
    const float* bm        = (const float*)d_in[10];
    float* out = (float*)d_out;

    const int* src = edge_idx;
    const int* dst = edge_idx + NE;

    // workspace layout
    ushort* xb   = (ushort*)d_ws;                       // NN*128 us
    ushort* Qb   = xb + (size_t)NN * DIM;               // NN*128 us
    ushort* KVb  = Qb + (size_t)NN * DIM;               // NN*256 us (K|V rows)
    ushort* aggb = KVb + (size_t)NN * 2 * DIM;          // NN*128 us
    uint*  ppack = (uint*)(aggb + (size_t)NN * DIM);    // NE uints
    uint2* pebp  = (uint2*)(ppack + NE);                // NE uint2 (bf16x4 eb)
    uint4* edata = (uint4*)(pebp + NE);                 // NE uint4 (CSR records)
    float* Wx    = (float*)(edata + NE);                // 16,384 f
    float* bprime= Wx + 16384;                          // 128 f
    short* BpQKV = (short*)(bprime + 128);              // 49,152 s
    short* BpOut = BpQKV + 49152;                       // 32,768 s
    int*   rowptr= (int*)(BpOut + 32768);               // 50,048 i (50001 used)
    int*   bkt_cnt    = rowptr + 50048;                 // 800 i (782 used)
    int*   bkt_base   = bkt_cnt + 800;                  // 800 i (783 used)
    int*   bkt_cursor = bkt_base + 800;                 // 800 i (782 used)

    hipMemsetAsync(bkt_cnt, 0, NBK * sizeof(int), stream);

    k1_kernel<<<K1_GRID, 256, 0, stream>>>(
        dst, bkt_cnt, Wq, Wk, Wv, BpQKV, Wo, Wm, bo, bm, Wx, bprime);

    bkt_scan_kernel<<<1, 256, 0, stream>>>(bkt_cnt, bkt_base, bkt_cursor, rowptr);

    k3_kernel<<<K3_GRID, 256, 0, stream>>>(
        src, dst, edge_attr, We, bkt_cursor, ppack, pebp, Wm, Wx, BpOut, x, xb);

    k4_kernel<<<K4_GRID, 256, 0, stream>>>(
        bkt_base, ppack, pebp, rowptr, edata, xb, BpQKV, Qb, KVb);

    attn_agg_kernel<<<NN / 4, 256, 0, stream>>>(Qb, KVb, rowptr, edata, aggb);

    out_mfma_kernel<<<GEMM_BLOCKS, 256, 0, stream>>>(xb, aggb, BpOut, bprime, out);
}

// Round 9
// 240.508 us; speedup vs baseline: 1.6843x; 1.0204x over previous
//
#include <hip/hip_runtime.h>
#include <hip/hip_bf16.h>
#include <math.h>

#define NN 50000
#define NE 800000
#define DIM 128
#define NH 4
#define HD 32
#define ATTN_SCALE 0.17677669529663687f   // 1/sqrt(32)
#define MTILE 64
#define NBK 782               // fine buckets of 64 nodes: dst>>6
#define PTS 2048              // edges per partition block
#define HBLKS 104             // hist blocks: shallow atomic chains

// K1: hist + pack_qkv + Wx/b'
#define K1_QKV_BASE 104           // 192 blocks
#define K1_WXB_BASE 296           // 65 blocks (2 rows each, 130 rows)
#define K1_GRID     361
// K3: partition + pack_out + x->bf16
#define K3_PART_N     391         // ceil(NE/PTS)
#define K3_PACKO_BASE 391         // 128 blocks
#define K3_XCVT_BASE  519         // 6250 blocks
#define K3_GRID       6769
// K4: CSR (one block per fine bucket) + QKV GEMM
#define K4_CSR_N 782
#define K4_GRID  1564
// fused attn+out: 16 nodes per 1024-thread block (50000 = 3125*16)
#define AO_GRID 3125

typedef unsigned int uint;
typedef unsigned short ushort;
typedef __attribute__((ext_vector_type(8))) short short8;   // 8 bf16 (4 VGPRs)
typedef __attribute__((ext_vector_type(4))) float f32x4;    // MFMA acc

__device__ inline ushort f2bf(float f) {
    __hip_bfloat16 h = __float2bfloat16(f);   // round-to-nearest
    return *(ushort*)&h;
}
__device__ inline float bflo(uint u) { return __uint_as_float(u << 16); }
__device__ inline float bfhi(uint u) { return __uint_as_float(u & 0xffff0000u); }

// ---------------------------------------------- K1: hist | pack_qkv | Wx,b'
// bkt_cnt pre-zeroed by memset. All three phases independent.
__global__ __launch_bounds__(256) void k1_kernel(
    const int* __restrict__ dst, int* __restrict__ bkt_cnt,
    const float* __restrict__ Wq, const float* __restrict__ Wk,
    const float* __restrict__ Wv, short* __restrict__ BpQKV,
    const float* __restrict__ Wo, const float* __restrict__ Wm,
    const float* __restrict__ bo, const float* __restrict__ bm,
    float* __restrict__ Wx, float* __restrict__ bprime)
{
    const int bid = blockIdx.x;
    const int tid = threadIdx.x;

    if (bid < HBLKS) {
        // fine-bucket histogram (grid-stride over edges)
        __shared__ int c[NBK];
        for (int l = tid; l < NBK; l += 256) c[l] = 0;
        __syncthreads();
        for (int e = bid * 256 + tid; e < NE; e += HBLKS * 256)
            atomicAdd(&c[dst[e] >> 6], 1);
        __syncthreads();
        for (int l = tid; l < NBK; l += 256)
            if (c[l]) atomicAdd(&bkt_cnt[l], c[l]);
    } else if (bid < K1_WXB_BASE) {
        // pack Wq/Wk/Wv into MFMA fragment order
        const int idx = (bid - K1_QKV_BASE) * 256 + tid;     // < 49152
        const int j = idx & 7, lane = (idx >> 3) & 63;
        const int rest = idx >> 9;                           // kc*24 + nt
        const int nt = rest % 24, kc = rest / 24;
        const int k = kc * 32 + (lane >> 4) * 8 + j;
        const int n = nt * 16 + (lane & 15);
        const float* W = (n < 128) ? Wq : (n < 256 ? Wk : Wv);
        BpQKV[idx] = (short)f2bf(W[k * 128 + (n & 127)]);
    } else {
        // Wx = Wo @ Wm2 (rows 128..255 of Wm); row 128 = b'
        const int r = (bid - K1_WXB_BASE) * 2 + (tid >> 7);
        const int j = tid & 127;
        if (r < 128) {
            float acc = 0.f;
            for (int t = 0; t < 128; ++t)
                acc = fmaf(Wo[r * 128 + t], Wm[(128 + t) * 128 + j], acc);
            Wx[r * 128 + j] = acc;
        } else if (r == 128) {
            float acc = bm[j];
            for (int t = 0; t < 128; ++t)
                acc = fmaf(bo[t], Wm[(128 + t) * 128 + j], acc);
            bprime[j] = acc;
        }
    }
}

// -------------------------------------- K2: parallel 782-bucket excl. scan
__global__ __launch_bounds__(256) void bkt_scan_kernel(
    const int* __restrict__ bkt_cnt,
    int* __restrict__ bkt_base, int* __restrict__ bkt_cursor,
    int* __restrict__ rowptr)
{
    __shared__ int part[256];
    const int tid = threadIdx.x;
    const int b0 = tid * 4;
    int v0 = 0, v1 = 0, v2 = 0, v3 = 0;
    if (b0 + 0 < NBK) v0 = bkt_cnt[b0 + 0];
    if (b0 + 1 < NBK) v1 = bkt_cnt[b0 + 1];
    if (b0 + 2 < NBK) v2 = bkt_cnt[b0 + 2];
    if (b0 + 3 < NBK) v3 = bkt_cnt[b0 + 3];
    const int s = v0 + v1 + v2 + v3;
    part[tid] = s;
    __syncthreads();
    for (int off = 1; off < 256; off <<= 1) {
        const int y = (tid >= off) ? part[tid - off] : 0;
        __syncthreads();
        part[tid] += y;
        __syncthreads();
    }
    const int ex = part[tid] - s;
    const int r0 = ex, r1 = ex + v0, r2 = ex + v0 + v1, r3 = ex + v0 + v1 + v2;
    if (b0 + 0 < NBK) { bkt_base[b0 + 0] = r0; bkt_cursor[b0 + 0] = r0; }
    if (b0 + 1 < NBK) { bkt_base[b0 + 1] = r1; bkt_cursor[b0 + 1] = r1; }
    if (b0 + 2 < NBK) { bkt_base[b0 + 2] = r2; bkt_cursor[b0 + 2] = r2; }
    if (b0 + 3 < NBK) { bkt_base[b0 + 3] = r3; bkt_cursor[b0 + 3] = r3; }
    if (tid == 255) bkt_base[NBK] = part[255];   // == NE
    if (tid == 0)   rowptr[NN] = NE;
}

// ------------------------------- K3: partition | pack_out | x->bf16 stream
__global__ __launch_bounds__(256) void k3_kernel(
    const int* __restrict__ src, const int* __restrict__ dst,
    const float* __restrict__ edge_attr, const float* __restrict__ We,
    int* __restrict__ bkt_cursor,
    uint* __restrict__ ppack, uint2* __restrict__ pebp,
    const float* __restrict__ Wm, const float* __restrict__ Wx,
    short* __restrict__ BpOut,
    const float* __restrict__ x, ushort* __restrict__ xb)
{
    const int bid = blockIdx.x;
    const int tid = threadIdx.x;

    if (bid < K3_PART_N) {
        __shared__ int cnt[NBK], rbase[NBK], cnt2[NBK];
        for (int l = tid; l < NBK; l += 256) cnt[l] = 0;
        __syncthreads();
        const int e0 = bid * PTS;
        #pragma unroll
        for (int it = 0; it < 8; ++it) {
            const int e = e0 + it * 256 + tid;
            if (e < NE) atomicAdd(&cnt[dst[e] >> 6], 1);
        }
        __syncthreads();
        for (int l = tid; l < NBK; l += 256) {
            const int c = cnt[l];
            rbase[l] = c ? atomicAdd(&bkt_cursor[l], c) : 0;
            cnt2[l] = 0;
        }
        __syncthreads();
        #pragma unroll
        for (int it = 0; it < 8; ++it) {
            const int e = e0 + it * 256 + tid;
            if (e < NE) {
                const int d = dst[e];
                const int b = d >> 6;
                const int r = atomicAdd(&cnt2[b], 1);
                const int pos = rbase[b] + r;
                ppack[pos] = (uint)src[e] | ((uint)(d & 63) << 16);
                const float a0 = edge_attr[e * 3 + 0];
                const float a1 = edge_attr[e * 3 + 1];
                const float a2 = edge_attr[e * 3 + 2];
                const float b0 = a0 * We[0] + a1 * We[4] + a2 * We[8];
                const float b1 = a0 * We[1] + a1 * We[5] + a2 * We[9];
                const float b2 = a0 * We[2] + a1 * We[6] + a2 * We[10];
                const float b3 = a0 * We[3] + a1 * We[7] + a2 * We[11];
                uint2 ep;
                ep.x = (uint)f2bf(b0) | ((uint)f2bf(b1) << 16);
                ep.y = (uint)f2bf(b2) | ((uint)f2bf(b3) << 16);
                pebp[pos] = ep;
            }
        }
    } else if (bid < K3_XCVT_BASE) {
        // pack epilogue B operand [Wm1; Wx]
        const int idx = (bid - K3_PACKO_BASE) * 256 + tid;   // < 32768
        const int j = idx & 7, lane = (idx >> 3) & 63;
        const int rest = idx >> 9;                           // kc*8 + nt
        const int nt = rest & 7, kc = rest >> 3;
        const int k = kc * 32 + (lane >> 4) * 8 + j;
        const int n = nt * 16 + (lane & 15);
        const float v = (k < 128) ? Wm[k * 128 + n] : Wx[(k - 128) * 128 + n];
        BpOut[idx] = (short)f2bf(v);
    } else {
        // x -> bf16 (one float4 per thread)
        const int i = (bid - K3_XCVT_BASE) * 256 + tid;      // < 1,600,000
        const float4 v = ((const float4*)x)[i];
        ushort4 o;
        o.x = f2bf(v.x); o.y = f2bf(v.y); o.z = f2bf(v.z); o.w = f2bf(v.w);
        ((ushort4*)xb)[i] = o;
    }
}

// ------------------------- K4: CSR scatter (1 block per fine bucket) | QKV
// Scatter emits ONE aligned 16B record per edge:
//   edata[pos] = { src, eb0|eb1 (bf16), eb2|eb3 (bf16), 0 }
__global__ __launch_bounds__(256) void k4_kernel(
    const int* __restrict__ bkt_base,
    const uint* __restrict__ ppack, const uint2* __restrict__ pebp,
    int* __restrict__ rowptr, uint4* __restrict__ edata,
    const ushort* __restrict__ xb, const short* __restrict__ BpQKV,
    ushort* __restrict__ Qb, ushort* __restrict__ KVb)
{
    const int bid = blockIdx.x;
    const int tid = threadIdx.x;

    if (bid < K4_CSR_N) {
        __shared__ int cnt[64];
        __shared__ int pre[64];
        const int base = bkt_base[bid];
        const int n = bkt_base[bid + 1] - base;
        const int node0 = bid << 6;

        if (tid < 64) cnt[tid] = 0;
        __syncthreads();
        for (int i = base + tid; i < base + n; i += 256)
            atomicAdd(&cnt[ppack[i] >> 16], 1);
        __syncthreads();

        if (tid < 64) {
            const int c = cnt[tid];
            int xsc = c;                      // inclusive scan over wave 0
            #pragma unroll
            for (int off = 1; off < 64; off <<= 1) {
                const int y = __shfl_up(xsc, off);
                if (tid >= off) xsc += y;
            }
            const int ex = base + xsc - c;    // exclusive
            pre[tid] = ex;
            const int g = node0 + tid;
            if (g < NN) rowptr[g] = ex;
        }
        __syncthreads();

        for (int i = base + tid; i < base + n; i += 256) {
            const uint v = ppack[i];
            const int pos = atomicAdd(&pre[v >> 16], 1);
            const uint2 ep = pebp[i];
            uint4 rec;
            rec.x = v & 0xFFFFu;
            rec.y = ep.x;
            rec.z = ep.y;
            rec.w = 0u;
            edata[pos] = rec;
        }
    } else {
        // ---- QKV MFMA: Q -> Qb; K,V interleaved per node in KVb (512B rows)
        const int qb = bid - K4_CSR_N;
        const int wave = tid >> 6;
        const int lane = tid & 63;
        const int m = lane & 15, quad = lane >> 4;
        const int row0w = qb * MTILE + wave * 16;
        const int arow = row0w + m;
        const bool rowok = arow < NN;

        short8 a[4];
        #pragma unroll
        for (int kc = 0; kc < 4; ++kc)
            a[kc] = rowok ? *(const short8*)(xb + (size_t)arow * 128 + kc * 32 + quad * 8)
                          : (short8)(0);

        const int NT = 24;
        for (int nt = 0; nt < NT; nt += 2) {
            f32x4 acc0 = {0.f, 0.f, 0.f, 0.f}, acc1 = {0.f, 0.f, 0.f, 0.f};
            #pragma unroll
            for (int kc = 0; kc < 4; ++kc) {
                const short8 b0 = *(const short8*)(BpQKV + ((size_t)(kc * NT + nt) * 64 + lane) * 8);
                const short8 b1 = *(const short8*)(BpQKV + ((size_t)(kc * NT + nt + 1) * 64 + lane) * 8);
                acc0 = __builtin_amdgcn_mfma_f32_16x16x32_bf16(a[kc], b0, acc0, 0, 0, 0);
                acc1 = __builtin_amdgcn_mfma_f32_16x16x32_bf16(a[kc], b1, acc1, 0, 0, 0);
            }
            #pragma unroll
            for (int t = 0; t < 2; ++t) {
                const f32x4 acc = t ? acc1 : acc0;
                const int c = (nt + t) * 16 + m;           // global col in [0,384)
                #pragma unroll
                for (int g = 0; g < 4; ++g) {
                    const int r = row0w + quad * 4 + g;
                    if (r < NN) {
                        if (c < 128) Qb[(size_t)r * 128 + c] = f2bf(acc[g]);
                        else        KVb[(size_t)r * 256 + (c - 128)] = f2bf(acc[g]);
                    }
                }
            }
        }
    }
}

// -------------------- FUSED attn + softmax + aggregate + OUT epilogue
// 1024-thread block = 16 waves = 16 nodes (50000 = 3125*16 exactly).
// Phase 1: wave wv runs the pinned attn loop for node blockIdx*16+wv,
//   writing agg to LDS (row padded to 136 ushorts to spread banks).
// Phase 2: waves 0..7 compute the 16x128 out tile with MFMA
//   (A = xb rows || LDS agg rows; B = BpOut), bias+ReLU, store fp32.
// Removes aggb round-trip (25.6 MB) + one launch + serial out tail.
__global__ __launch_bounds__(1024) void attn_out_kernel(
    const ushort* __restrict__ Qb, const ushort* __restrict__ KVb,
    const int* __restrict__ rowptr, const uint4* __restrict__ edata,
    const ushort* __restrict__ xb, const short* __restrict__ BpOut,
    const float* __restrict__ bprime, float* __restrict__ out)
{
    __shared__ ushort sagg[16][136];   // 4352 B, +8 pad breaks bank alias
    const int tid = threadIdx.x;
    const int wv = tid >> 6;          // 0..15: wave = node slot
    const int lane = tid & 63;
    const int node0 = blockIdx.x * 16;

    // ================= phase 1: attention for node d = node0 + wv =========
    {
        const int d = node0 + wv;
        const int g = lane >> 4;          // edge slot within quad
        const int t = lane & 15;          // 8-dim chunk index
        const int h = t >> 2;             // head of this chunk
        const int begin = rowptr[d];
        const int end   = rowptr[d + 1];

        const uint4 uq = *(const uint4*)(Qb + (size_t)d * DIM + 8 * t);
        const float q0 = bflo(uq.x), q1 = bfhi(uq.x);
        const float q2 = bflo(uq.y), q3 = bfhi(uq.y);
        const float q4 = bflo(uq.z), q5 = bfhi(uq.z);
        const float q6 = bflo(uq.w), q7 = bfhi(uq.w);

        float ss = 0.f;
        float a0 = 0.f, a1 = 0.f, a2 = 0.f, a3 = 0.f;
        float a4 = 0.f, a5 = 0.f, a6 = 0.f, a7 = 0.f;

        if (begin < end) {
            int ec = begin + g;
            if (ec >= end) ec = end - 1;
            uint4 rec = edata[ec];

            for (int p = begin; p < end; p += 4) {
                const bool ok = (p + g) < end;
                const int pn = p + 4;
                uint4 recn = rec;
                if (pn < end) {
                    int en = pn + g;
                    if (en >= end) en = end - 1;
                    recn = edata[en];
                }

                const int s = (int)rec.x;
                const uint wrd = (h & 2) ? rec.z : rec.y;
                const float eb = (h & 1) ? bfhi(wrd) : bflo(wrd);

                const ushort* kv = KVb + (size_t)s * 256 + 8 * t;
                const uint4 uk = *(const uint4*)(kv);
                const uint4 uv = *(const uint4*)(kv + 128);

                float da = q0 * bflo(uk.x);
                float db = q1 * bfhi(uk.x);
                da = fmaf(q2, bflo(uk.y), da);
                db = fmaf(q3, bfhi(uk.y), db);
                da = fmaf(q4, bflo(uk.z), da);
                db = fmaf(q5, bfhi(uk.z), db);
                da = fmaf(q6, bflo(uk.w), da);
                db = fmaf(q7, bfhi(uk.w), db);
                float part = da + db;
                part += __shfl_xor(part, 1);
                part += __shfl_xor(part, 2);

                float a = fmaf(part, ATTN_SCALE, eb);
                a = (a >= 0.f) ? a : 0.2f * a;
                const float w = ok ? __expf(a) : 0.f;

                ss += w;
                a0 = fmaf(w, bflo(uv.x), a0);
                a1 = fmaf(w, bfhi(uv.x), a1);
                a2 = fmaf(w, bflo(uv.y), a2);
                a3 = fmaf(w, bfhi(uv.y), a3);
                a4 = fmaf(w, bflo(uv.z), a4);
                a5 = fmaf(w, bfhi(uv.z), a5);
                a6 = fmaf(w, bflo(uv.w), a6);
                a7 = fmaf(w, bfhi(uv.w), a7);

                rec = recn;
            }
        }

        ss += __shfl_xor(ss, 16);
        ss += __shfl_xor(ss, 32);
        a0 += __shfl_xor(a0, 16); a0 += __shfl_xor(a0, 32);
        a1 += __shfl_xor(a1, 16); a1 += __shfl_xor(a1, 32);
        a2 += __shfl_xor(a2, 16); a2 += __shfl_xor(a2, 32);
        a3 += __shfl_xor(a3, 16); a3 += __shfl_xor(a3, 32);
        a4 += __shfl_xor(a4, 16); a4 += __shfl_xor(a4, 32);
        a5 += __shfl_xor(a5, 16); a5 += __shfl_xor(a5, 32);
        a6 += __shfl_xor(a6, 16); a6 += __shfl_xor(a6, 32);
        a7 += __shfl_xor(a7, 16); a7 += __shfl_xor(a7, 32);

        if (g == 0) {
            const float inv = 1.f / fmaxf(ss, 1e-12f);
            uint4 o;
            o.x = (uint)f2bf(a0 * inv) | ((uint)f2bf(a1 * inv) << 16);
            o.y = (uint)f2bf(a2 * inv) | ((uint)f2bf(a3 * inv) << 16);
            o.z = (uint)f2bf(a4 * inv) | ((uint)f2bf(a5 * inv) << 16);
            o.w = (uint)f2bf(a6 * inv) | ((uint)f2bf(a7 * inv) << 16);
            *(uint4*)(&sagg[wv][8 * t]) = o;
        }
    }

    __syncthreads();

    // ================= phase 2: out tile (waves 0..7, nt = wv) ============
    if (wv < 8) {
        const int m = lane & 15, quad = lane >> 4;
        const int arow = node0 + m;              // always < NN (NN%16==0)

        short8 a[8];
        #pragma unroll
        for (int kc = 0; kc < 4; ++kc)
            a[kc] = *(const short8*)(xb + (size_t)arow * 128 + kc * 32 + quad * 8);
        #pragma unroll
        for (int kc = 0; kc < 4; ++kc)
            a[4 + kc] = *(const short8*)(&sagg[m][kc * 32 + quad * 8]);

        const int NT = 8;
        const int nt = wv;
        f32x4 acc = {0.f, 0.f, 0.f, 0.f};
        #pragma unroll
        for (int kc = 0; kc < 8; ++kc) {
            const short8 b0 = *(const short8*)(BpOut + ((size_t)(kc * NT + nt) * 64 + lane) * 8);
            acc = __builtin_amdgcn_mfma_f32_16x16x32_bf16(a[kc], b0, acc, 0, 0, 0);
        }
        const int c = nt * 16 + m;               // col in [0,128)
        const float bb = bprime[c];
        #pragma unroll
        for (int g2 = 0; g2 < 4; ++g2) {
            const int r = node0 + quad * 4 + g2;
            out[(size_t)r * 128 + c] = fmaxf(acc[g2] + bb, 0.f);
        }
    }
}

// ----------------------------------------------------------------- launch
extern "C" void kernel_launch(void* const* d_in, const int* in_sizes, int n_in,
                              void* d_out, int out_size, void* d_ws, size_t ws_size,
                              hipStream_t stream)
{
    const float* x         = (const float*)d_in[0];
    const int*   edge_idx  = (const int*)d_in[1];   // [2,E]: row0=src, row1=dst
    const float* edge_attr = (const float*)d_in[2];
    const float* Wq        = (const float*)d_in[3];
    const float* Wk        = (const float*)d_in[4];
    const float* Wv        = (const float*)d_in[5];
    const float* We        = (const float*)d_in[6];
    const float* Wo        = (const float*)d_in[7];
    const float* bo        = (const float*)d_in[8];
    const float* Wm        = (const float*)d_in[9];
    const float* bm        = (const float*)d_in[10];
    float* out = (float*)d_out;

    const int* src = edge_idx;
    const int* dst = edge_idx + NE;

    // workspace layout
    ushort* xb   = (ushort*)d_ws;                       // NN*128 us
    ushort* Qb   = xb + (size_t)NN * DIM;               // NN*128 us
    ushort* KVb  = Qb + (size_t)NN * DIM;               // NN*256 us (K|V rows)
    uint*  ppack = (uint*)(KVb + (size_t)NN * 2 * DIM); // NE uints
    uint2* pebp  = (uint2*)(ppack + NE);                // NE uint2 (bf16x4 eb)
    uint4* edata = (uint4*)(pebp + NE);                 // NE uint4 (CSR records)
    float* Wx    = (float*)(edata + NE);                // 16,384 f
    float* bprime= Wx + 16384;                          // 128 f
    short* BpQKV = (short*)(bprime + 128);              // 49,152 s
    short* BpOut = BpQKV + 49152;                       // 32,768 s
    int*   rowptr= (int*)(BpOut + 32768);               // 50,048 i (50001 used)
    int*   bkt_cnt    = rowptr + 50048;                 // 800 i (782 used)
    int*   bkt_base   = bkt_cnt + 800;                  // 800 i (783 used)
    int*   bkt_cursor = bkt_base + 800;                 // 800 i (782 used)

    hipMemsetAsync(bkt_cnt, 0, NBK * sizeof(int), stream);

    k1_kernel<<<K1_GRID, 256, 0, stream>>>(
        dst, bkt_cnt, Wq, Wk, Wv, BpQKV, Wo, Wm, bo, bm, Wx, bprime);

    bkt_scan_kernel<<<1, 256, 0, stream>>>(bkt_cnt, bkt_base, bkt_cursor, rowptr);

    k3_kernel<<<K3_GRID, 256, 0, stream>>>(
        src, dst, edge_attr, We, bkt_cursor, ppack, pebp, Wm, Wx, BpOut, x, xb);

    k4_kernel<<<K4_GRID, 256, 0, stream>>>(
        bkt_base, ppack, pebp, rowptr, edata, xb, BpQKV, Qb, KVb);

    attn_out_kernel<<<AO_GRID, 1024, 0, stream>>>(
        Qb, KVb, rowptr, edata, xb, BpOut, bprime, out);
}